// Round 2
// baseline (581.818 us; speedup 1.0000x reference)
//
#include <hip/hip_runtime.h>
#include <cstdint>
#include <cstddef>

#define NSAMP 4096
#define KDIM  512
#define TOT   49536   // 3 * (128*128 + 128)

typedef __attribute__((ext_vector_type(8))) __bf16 bf16x8;
typedef __attribute__((ext_vector_type(4))) __bf16 bf16x4;
typedef __attribute__((ext_vector_type(4))) float  f32x4;

// ---------------------------------------------------------------------------
// fp32 -> bf16 cast, 4 elements per thread (float4 read, 8B write)
// ---------------------------------------------------------------------------
__global__ void cast_bf16(const float* __restrict__ in, __bf16* __restrict__ out, int n4) {
    int i = blockIdx.x * blockDim.x + threadIdx.x;
    int stride = gridDim.x * blockDim.x;
    for (; i < n4; i += stride) {
        float4 v = ((const float4*)in)[i];
        bf16x4 o = { (__bf16)v.x, (__bf16)v.y, (__bf16)v.z, (__bf16)v.w };
        ((bf16x4*)out)[i] = o;
    }
}

// ---------------------------------------------------------------------------
// Hypernetwork GEMM (chunked over samples):
//   C[m][n] = sum_k A[m][k] * B[n][k] + bias[n],  m in [0,Mchunk), n in [0,TOT)
// A = int_x bf16 (chunk x 512, row base passed in), B = W bf16 (49536 x 512),
// C = temp chunk bf16 (chunk x 49536).
// m97 structure: 128x128 tile, BK=32, 4 waves (2x2) x 4x4 16x16x32 frags,
// global_load_lds width=16 staging, 2-barrier K-loop.
// ---------------------------------------------------------------------------
__global__ __launch_bounds__(256) void hyper_gemm(
    const __bf16* __restrict__ A, const __bf16* __restrict__ B,
    const float* __restrict__ bias, __bf16* __restrict__ C)
{
    __shared__ __bf16 As[128 * 32];
    __shared__ __bf16 Bs[128 * 32];

    const int tid   = threadIdx.x;
    const int lane  = tid & 63;
    const int wv    = tid >> 6;       // 0..3
    const int quad  = lane >> 4;      // 0..3
    const int r16   = lane & 15;      // 0..15
    const int waveM = wv >> 1;        // 0..1
    const int waveN = wv & 1;         // 0..1

    const int m0 = blockIdx.y * 128;  // chunk-local row
    const int n0 = blockIdx.x * 128;

    f32x4 acc[4][4] = {};

    for (int kt = 0; kt < KDIM / 32; ++kt) {
        const int k0 = kt * 32;
        // --- stage 128x32 A-tile and B-tile via async global->LDS (16B/lane)
#pragma unroll
        for (int c = 0; c < 2; ++c) {
            int idx = (wv * 2 + c) * 64 + lane;   // 0..511
            int row = idx >> 2;                   // 0..127
            int col = (idx & 3) << 3;             // 0,8,16,24
            const __bf16* ga = A + (size_t)(m0 + row) * KDIM + (k0 + col);
            __builtin_amdgcn_global_load_lds(
                (__attribute__((address_space(1))) void*)ga,
                (__attribute__((address_space(3))) void*)(As + (wv * 2 + c) * 512),
                16, 0, 0);
            const __bf16* gb = B + (size_t)(n0 + row) * KDIM + (k0 + col);
            __builtin_amdgcn_global_load_lds(
                (__attribute__((address_space(1))) void*)gb,
                (__attribute__((address_space(3))) void*)(Bs + (wv * 2 + c) * 512),
                16, 0, 0);
        }
        __syncthreads();

        bf16x8 af[4], bf[4];
#pragma unroll
        for (int i = 0; i < 4; ++i)
            af[i] = *(const bf16x8*)(As + (waveM * 64 + i * 16 + r16) * 32 + quad * 8);
#pragma unroll
        for (int j = 0; j < 4; ++j)
            bf[j] = *(const bf16x8*)(Bs + (waveN * 64 + j * 16 + r16) * 32 + quad * 8);

#pragma unroll
        for (int i = 0; i < 4; ++i)
#pragma unroll
            for (int j = 0; j < 4; ++j)
                acc[i][j] = __builtin_amdgcn_mfma_f32_16x16x32_bf16(af[i], bf[j], acc[i][j], 0, 0, 0);
        __syncthreads();
    }

    // --- epilogue: C/D layout col=lane&15, row=(lane>>4)*4+reg. Fuse bias, cast bf16.
#pragma unroll
    for (int j = 0; j < 4; ++j) {
        int n = n0 + waveN * 64 + j * 16 + r16;
        float bb = bias[n];
#pragma unroll
        for (int i = 0; i < 4; ++i) {
            int mbase = m0 + waveM * 64 + i * 16 + quad * 4;
#pragma unroll
            for (int rr = 0; rr < 4; ++rr) {
                C[(size_t)(mbase + rr) * TOT + n] = (__bf16)(acc[i][j][rr] + bb);
            }
        }
    }
}

// ---------------------------------------------------------------------------
// Stage 2: per-sample 3-layer MLP with hypernetwork weights from temp chunk.
// One block (256 threads = 4 waves) per sample. Wave wv handles p-range
// [wv*32, wv*32+32). Within wave: lane l, pg=l>>4 -> p = wv*32 + 4i + pg,
// qg=l&15 -> q in [8qg, 8qg+8). Every weight load is 16B (wave reads 1KB
// contiguous). Reduce: shfl_xor(16,32) intra-wave, LDS partials cross-wave.
// ---------------------------------------------------------------------------
__global__ __launch_bounds__(256) void mlp_kernel(
    const float* __restrict__ x, const __bf16* __restrict__ temp,
    float* __restrict__ out, int samp0)
{
    const int n   = samp0 + blockIdx.x;   // global sample index
    const int tid = threadIdx.x;
    const int wv  = tid >> 6;             // 0..3
    const int l   = tid & 63;
    const int pg  = l >> 4;               // 0..3
    const int qg  = l & 15;               // 0..15

    __shared__ float h[128];
    __shared__ float partial[4][128];

    if (tid < 64) ((float2*)h)[tid] = ((const float2*)(x + (size_t)n * 128))[tid];

    const __bf16* row = temp + (size_t)blockIdx.x * TOT;   // chunk-local temp row
    int cum = 0;
#pragma unroll
    for (int layer = 0; layer < 3; ++layer) {
        const __bf16* bias = row + cum;
        const __bf16* wgt  = row + cum + 128;
        float acc[8] = {0, 0, 0, 0, 0, 0, 0, 0};
        __syncthreads();   // h ready
#pragma unroll
        for (int i = 0; i < 8; ++i) {
            int p = wv * 32 + i * 4 + pg;
            bf16x8 w = *(const bf16x8*)(wgt + (size_t)p * 128 + qg * 8);
            float hp = h[p];
#pragma unroll
            for (int j = 0; j < 8; ++j) acc[j] += (float)w[j] * hp;
        }
#pragma unroll
        for (int j = 0; j < 8; ++j) {
            acc[j] += __shfl_xor(acc[j], 16);
            acc[j] += __shfl_xor(acc[j], 32);
        }
        if (pg == 0) {
#pragma unroll
            for (int j = 0; j < 8; ++j) partial[wv][qg * 8 + j] = acc[j];
        }
        __syncthreads();   // partials ready; everyone done reading h
        if (tid < 128) {
            float v = partial[0][tid] + partial[1][tid] + partial[2][tid] + partial[3][tid]
                    + (float)bias[tid];
            if (layer < 2) v = fmaxf(v, 0.f);
            h[tid] = v;
        }
        cum += 128 + 128 * 128;
    }
    __syncthreads();
    if (tid < 64) ((float2*)(out + (size_t)n * 128))[tid] = ((const float2*)h)[tid];
}

// ---------------------------------------------------------------------------
extern "C" void kernel_launch(void* const* d_in, const int* in_sizes, int n_in,
                              void* d_out, int out_size, void* d_ws, size_t ws_size,
                              hipStream_t stream) {
    const float* int_x = (const float*)d_in[0];  // 4096 x 512
    const float* x     = (const float*)d_in[1];  // 4096 x 128
    const float* W     = (const float*)d_in[2];  // 49536 x 512
    const float* b     = (const float*)d_in[3];  // 49536
    float* out = (float*)d_out;                  // 4096 x 128

    // workspace layout (bf16): A_bf (4 MB) | W_bf (50.7 MB) | temp chunk
    char* ws = (char*)d_ws;
    __bf16* A_bf = (__bf16*)ws;
    size_t offA = (size_t)NSAMP * KDIM * 2;
    __bf16* W_bf = (__bf16*)(ws + offA);
    size_t offW = offA + (size_t)TOT * KDIM * 2;
    __bf16* temp = (__bf16*)(ws + offW);

    // Adaptive chunk: largest of {1024,512,256,128} whose temp fits remaining
    // ws. Deterministic given ws_size -> identical work every call (capture-safe).
    // Cap at 1024 so the temp chunk (<=101.5 MB) stays L3-resident between the
    // GEMM write and the MLP read.
    size_t remain = (ws_size > offW) ? (ws_size - offW) : 0;
    int chunk = 128;
    for (int c = 1024; c >= 128; c >>= 1) {
        if ((size_t)c * TOT * 2 <= remain) { chunk = c; break; }
    }

    int nA4 = NSAMP * KDIM / 4;
    cast_bf16<<<(nA4 + 255) / 256, 256, 0, stream>>>(int_x, A_bf, nA4);
    int nW4 = TOT * KDIM / 4;
    cast_bf16<<<(nW4 + 255) / 256, 256, 0, stream>>>(W, W_bf, nW4);

    for (int samp0 = 0; samp0 < NSAMP; samp0 += chunk) {
        dim3 grid(TOT / 128, chunk / 128);   // 387 x (chunk/128)
        hyper_gemm<<<grid, 256, 0, stream>>>(A_bf + (size_t)samp0 * KDIM, W_bf, b, temp);
        mlp_kernel<<<chunk, 256, 0, stream>>>(x, temp, out, samp0);
    }
}